// Round 3
// baseline (247.113 us; speedup 1.0000x reference)
//
#include <hip/hip_runtime.h>
#include <math.h>

#define N_NODES 8192
#define C_CLS   16
#define JC      256            // j-chunk staged in LDS per iteration
#define JSPLIT  4              // j-dimension split across blocks
#define JSLICE  (N_NODES / JSPLIT)   // 2048 columns per block
#define RPB     16             // rows per block (4 waves x 4 rows)
#define MAXRG   (N_NODES / RPB)      // 512 row-groups max

// Per active block we emit RPB rows x 17 floats (16 dots + rowsum), padded
// to 20 for clean float4 access: layout Hrow[(rg*JSPLIT+js)*RPB*20 + ...]
#define ROWW    20

// ---- workspace layout (bytes) ----
#define WS_INPUTS 0                  // 8192*16*4              = 524288
#define WS_HROW   524288             // 2048*16*20*4           = 2621440
#define WS_IDX    3145728            // 8192*4                 = 32768
#define WS_COUNTS 3178496            // 16*4
#define WS_NM     3178560            // 4

// ---------------------------------------------------------------------------
// A: blocks 0..31: inputs = softmax(init_inputs) blended with one-hot(y).
//    block 32: ballot-based masked-row compaction + per-class counts.
// ---------------------------------------------------------------------------
__global__ __launch_bounds__(256) void k_prep(const float* __restrict__ init_in,
                                              const int* __restrict__ y,
                                              const int* __restrict__ mask,
                                              float* __restrict__ inputs,
                                              int* __restrict__ idx,
                                              int* __restrict__ counts,
                                              int* __restrict__ nmp) {
  if (blockIdx.x < 32) {
    int i = blockIdx.x * 256 + threadIdx.x;
    const float4* p = (const float4*)(init_in + (size_t)i * C_CLS);
    float v[16];
    float4 a0 = p[0], a1 = p[1], a2 = p[2], a3 = p[3];
    v[0]=a0.x; v[1]=a0.y; v[2]=a0.z; v[3]=a0.w;
    v[4]=a1.x; v[5]=a1.y; v[6]=a1.z; v[7]=a1.w;
    v[8]=a2.x; v[9]=a2.y; v[10]=a2.z; v[11]=a2.w;
    v[12]=a3.x; v[13]=a3.y; v[14]=a3.z; v[15]=a3.w;
    float mx = v[0];
#pragma unroll
    for (int c = 1; c < 16; ++c) mx = fmaxf(mx, v[c]);
    float s = 0.f;
#pragma unroll
    for (int c = 0; c < 16; ++c) { v[c] = expf(v[c] - mx); s += v[c]; }
    float inv = 1.0f / s;
    if (mask[i] != 0) {
      int yc = y[i];
#pragma unroll
      for (int c = 0; c < 16; ++c) v[c] = (c == yc) ? 1.0f : 0.0f;
    } else {
#pragma unroll
      for (int c = 0; c < 16; ++c) v[c] *= inv;
    }
    float4* o = (float4*)(inputs + (size_t)i * C_CLS);
    o[0] = make_float4(v[0], v[1], v[2], v[3]);
    o[1] = make_float4(v[4], v[5], v[6], v[7]);
    o[2] = make_float4(v[8], v[9], v[10], v[11]);
    o[3] = make_float4(v[12], v[13], v[14], v[15]);
    return;
  }
  // ---- compaction block (4 waves, 2048 rows each) ----
  __shared__ unsigned long long bm_s[4][32];
  __shared__ int wtot[4];
  __shared__ int wcls[4][16];
  int lane = threadIdx.x & 63, w = threadIdx.x >> 6;
  int base = w * 2048;
  int cw = 0;
  int ccls[16];
#pragma unroll
  for (int c = 0; c < 16; ++c) ccls[c] = 0;
  for (int k = 0; k < 32; ++k) {
    int r = base + k * 64 + lane;
    int mv = mask[r];
    int yv = y[r];
    unsigned long long bm = __ballot(mv != 0);
    if (lane == 0) bm_s[w][k] = bm;
    cw += __popcll(bm);
#pragma unroll
    for (int c = 0; c < 16; ++c)
      ccls[c] += __popcll(__ballot((mv != 0) && (yv == c)));
  }
  if (lane == 0) {
    wtot[w] = cw;
#pragma unroll
    for (int c = 0; c < 16; ++c) wcls[w][c] = ccls[c];
  }
  __syncthreads();
  int run = 0;
  for (int u = 0; u < 4; ++u) run += (u < w) ? wtot[u] : 0;
  for (int k = 0; k < 32; ++k) {
    unsigned long long bm = bm_s[w][k];
    int r = base + k * 64 + lane;
    if ((bm >> lane) & 1ull) {
      int pos = __popcll(bm & ((1ull << lane) - 1ull));
      idx[run + pos] = r;
    }
    run += __popcll(bm);
  }
  if (threadIdx.x < 16)
    counts[threadIdx.x] = wcls[0][threadIdx.x] + wcls[1][threadIdx.x] +
                          wcls[2][threadIdx.x] + wcls[3][threadIdx.x];
  if (threadIdx.x == 0) nmp[0] = wtot[0] + wtot[1] + wtot[2] + wtot[3];
}

// ---------------------------------------------------------------------------
// B: per-row dot partials over a j-slice. Block (rg, js): 16 rows x 2048 cols.
// Emits 16 rows x (16 dot partials + rowsum partial), UNNORMALIZED.
// ---------------------------------------------------------------------------
__global__ __launch_bounds__(256) void k_main(const float* __restrict__ A,
                                              const float* __restrict__ inputs,
                                              const int* __restrict__ idx,
                                              const int* __restrict__ nmp,
                                              float* __restrict__ Hrow) {
  __shared__ float lin[JC * 16];       // 16 KiB staged inputs chunk (swizzled)
  int tid = threadIdx.x, wid = tid >> 6, lane = tid & 63;
  int nm = *nmp;
  int bid = blockIdx.x;
  int rg = bid >> 2, js = bid & 3;
  if (rg * RPB >= nm) return;          // whole-block uniform

  int rbase = rg * RPB + wid * 4;
  int rows[4]; bool valid[4];
  const float* arow[4];
#pragma unroll
  for (int r = 0; r < 4; ++r) {
    int g = rbase + r;
    valid[r] = (g < nm);
    rows[r] = valid[r] ? idx[g] : 0;
    arow[r] = A + (size_t)rows[r] * N_NODES;
  }

  float acc[4][16];
  float asum[4] = {0.f, 0.f, 0.f, 0.f};
#pragma unroll
  for (int r = 0; r < 4; ++r)
#pragma unroll
    for (int c = 0; c < 16; ++c) acc[r][c] = 0.f;

  int jbase = js * JSLICE;
  for (int ch = 0; ch < JSLICE / JC; ++ch) {
    int j0 = jbase + ch * JC;
#pragma unroll
    for (int s = 0; s < (JC * 16) / (256 * 4); ++s) {
      int G = s * 256 + tid;
      float4 v = *(const float4*)(inputs + (size_t)j0 * 16 + (size_t)G * 4);
      int slot = G ^ ((G >> 4) & 7);
      *(float4*)(lin + slot * 4) = v;
    }
    __syncthreads();
    {
      int jl = lane * 4;               // JC == 256 -> single stage
      float4 a4[4];
#pragma unroll
      for (int r = 0; r < 4; ++r) {
        if (valid[r]) a4[r] = *(const float4*)(arow[r] + j0 + jl);
        else a4[r] = make_float4(0.f, 0.f, 0.f, 0.f);
      }
#pragma unroll
      for (int jj = 0; jj < 4; ++jj) {
        int g0 = (jl + jj) * 4;
        int sw = lane & 7;             // == ((jl+jj)>>2)&7
        float in[16];
#pragma unroll
        for (int c4 = 0; c4 < 4; ++c4) {
          float4 v = *(const float4*)(lin + ((g0 + c4) ^ sw) * 4);
          in[c4 * 4 + 0] = v.x; in[c4 * 4 + 1] = v.y;
          in[c4 * 4 + 2] = v.z; in[c4 * 4 + 3] = v.w;
        }
#pragma unroll
        for (int r = 0; r < 4; ++r) {
          float av = (jj == 0) ? a4[r].x : (jj == 1) ? a4[r].y
                   : (jj == 2) ? a4[r].z : a4[r].w;
          asum[r] += av;
#pragma unroll
          for (int c = 0; c < 16; ++c) acc[r][c] = fmaf(av, in[c], acc[r][c]);
        }
      }
    }
    __syncthreads();
  }

  // lane-reduce and emit per-row partials (no normalization here)
#pragma unroll
  for (int r = 0; r < 4; ++r) {
    float s = asum[r];
    float t16[16];
#pragma unroll
    for (int c = 0; c < 16; ++c) t16[c] = acc[r][c];
    for (int m = 1; m < 64; m <<= 1) {
      s += __shfl_xor(s, m, 64);
#pragma unroll
      for (int c = 0; c < 16; ++c) t16[c] += __shfl_xor(t16[c], m, 64);
    }
    float* dst = Hrow + ((size_t)bid * RPB + wid * 4 + r) * ROWW;
    if (lane < 16) dst[lane] = t16[lane];
    if (lane == 16) dst[16] = s;
  }
}

// ---------------------------------------------------------------------------
// C: combine row partials across j-slices, normalize by full rowsum, scatter
// by class, divide by counts, NaN repair, single-wave Sinkhorn.
// ---------------------------------------------------------------------------
__global__ __launch_bounds__(256) void k_final(const float* __restrict__ Hrow,
                                               const int* __restrict__ counts,
                                               const int* __restrict__ nmp,
                                               const int* __restrict__ idx,
                                               const int* __restrict__ y,
                                               float* __restrict__ out) {
  __shared__ float hp[4][16][16];      // per-wave class accumulators
  __shared__ float S[256];
  __shared__ float S2[256];
  __shared__ float Sn[256];
  __shared__ float rs[16];
  __shared__ int nc[16];
  int t = threadIdx.x;
  int wid = t >> 6, lane = t & 63;
  int nm = *nmp;

  ((float*)hp)[t] = 0.f; ((float*)hp)[t + 256] = 0.f;
  ((float*)hp)[t + 512] = 0.f; ((float*)hp)[t + 768] = 0.f;
  __syncthreads();

  // Each wave processes rows nm-strided by 4 waves; 4 lanes per row
  // (lane>>4 selects row-in-group of 4, lane&15 the class column).
  // Simpler: each wave handles rows i = wid + 4*k; 16 lanes active per row.
  // To keep all 64 lanes busy: process 4 rows per iteration per wave.
  int rgrp = lane >> 4;        // 0..3: which of 4 rows this lane group handles
  int col  = lane & 15;
  for (int i0 = wid * 4; i0 < nm; i0 += 16) {
    int i = i0 + rgrp;         // global compacted-row index
    float dot = 0.f, rsum = 0.f;
    if (i < nm) {
      int rg = i / RPB, ri = i % RPB;
#pragma unroll
      for (int js = 0; js < JSPLIT; ++js) {
        const float* src = Hrow + ((size_t)(rg * JSPLIT + js) * RPB + ri) * ROWW;
        dot  += src[col];
        rsum += src[16];
      }
      float inv = 1.0f / rsum;
      int cls = y[idx[i]];
      // accumulate into this wave's class matrix; 4 lane-groups may target
      // the same class -> serialize via LDS adds per lane-group (no atomics:
      // lane-groups write disjoint temp then wave reduces). Use shfl instead:
      dot *= inv;
      // scatter: only one lane-group at a time adds to hp (avoids collisions)
#pragma unroll
      for (int g = 0; g < 4; ++g) {
        if (rgrp == g) hp[wid][cls][col] += dot;
        __builtin_amdgcn_wave_barrier();   // keep lane-groups ordered
      }
    } else {
#pragma unroll
      for (int g = 0; g < 4; ++g) __builtin_amdgcn_wave_barrier();
    }
  }
  __syncthreads();
  int a = t >> 4, c = t & 15;
  float s = hp[0][a][c] + hp[1][a][c] + hp[2][a][c] + hp[3][a][c];
  float cnt = (float)counts[a];
  float H = s / cnt;                    // 0/0 -> NaN, matches reference
  S[t] = H;
  __syncthreads();
  float HT = S[c * 16 + a];
  if (isnan(H)) H = HT;
  bool nan2 = isnan(H);
  float Hz = nan2 ? 0.f : H;
  S2[t] = Hz;
  Sn[t] = nan2 ? 1.f : 0.f;
  __syncthreads();
  if (t < 16) {
    float rsum = 0.f, ns = 0.f;
    for (int k = 0; k < 16; ++k) { rsum += S2[t * 16 + k]; ns += Sn[t * 16 + k]; }
    rs[t] = rsum; nc[t] = (int)ns;
  }
  __syncthreads();
  float miss = (1.0f - rs[a]) / (float)max(nc[a], 1);
  H = nan2 ? miss : Hz;
  __syncthreads();
  S[t] = H;
  __syncthreads();
  // single-wave Sinkhorn: lane holds col (lane&15), rows rgq*4+k
  if (t < 64) {
    int lcol = t & 15, rgq = t >> 4;
    float h[4];
#pragma unroll
    for (int k = 0; k < 4; ++k) h[k] = S[(rgq * 4 + k) * 16 + lcol];
    for (int it = 0; it < 3000; ++it) {
      float p0 = h[0], p1 = h[1], p2 = h[2], p3 = h[3];
      float cs = (h[0] + h[1]) + (h[2] + h[3]);
      cs += __shfl_xor(cs, 16, 64);
      cs += __shfl_xor(cs, 32, 64);
      float rcs = __builtin_amdgcn_rcpf(cs);
#pragma unroll
      for (int k = 0; k < 4; ++k) h[k] *= rcs;
#pragma unroll
      for (int k = 0; k < 4; ++k) {
        float rv = h[k];
        rv += __shfl_xor(rv, 1, 64);
        rv += __shfl_xor(rv, 2, 64);
        rv += __shfl_xor(rv, 4, 64);
        rv += __shfl_xor(rv, 8, 64);
        h[k] *= __builtin_amdgcn_rcpf(rv);
      }
      float d = fabsf(h[0] - p0) + fabsf(h[1] - p1) +
                fabsf(h[2] - p2) + fabsf(h[3] - p3);
      d += __shfl_xor(d, 1, 64);  d += __shfl_xor(d, 2, 64);
      d += __shfl_xor(d, 4, 64);  d += __shfl_xor(d, 8, 64);
      d += __shfl_xor(d, 16, 64); d += __shfl_xor(d, 32, 64);
      if (d < 1e-5f) break;
    }
#pragma unroll
    for (int k = 0; k < 4; ++k) out[(rgq * 4 + k) * 16 + lcol] = h[k];
  }
}

// ---------------------------------------------------------------------------
extern "C" void kernel_launch(void* const* d_in, const int* in_sizes, int n_in,
                              void* d_out, int out_size, void* d_ws, size_t ws_size,
                              hipStream_t stream) {
  const float* A       = (const float*)d_in[0];  // raw_adj  (8192*8192)
  const float* init_in = (const float*)d_in[1];  // init_inputs (8192*16)
  const int*   y       = (const int*)d_in[2];    // (8192)
  const int*   mask    = (const int*)d_in[3];    // (8192)
  float* out = (float*)d_out;                    // (16*16)
  char*  ws  = (char*)d_ws;
  float* inputs = (float*)(ws + WS_INPUTS);
  float* Hrow   = (float*)(ws + WS_HROW);
  int*   idx    = (int*)(ws + WS_IDX);
  int*   counts = (int*)(ws + WS_COUNTS);
  int*   nmp    = (int*)(ws + WS_NM);

  k_prep<<<33, 256, 0, stream>>>(init_in, y, mask, inputs, idx, counts, nmp);
  k_main<<<MAXRG * JSPLIT, 256, 0, stream>>>(A, inputs, idx, nmp, Hrow);
  k_final<<<1, 256, 0, stream>>>(Hrow, counts, nmp, idx, y, out);
}

// Round 4
// 150.698 us; speedup vs baseline: 1.6398x; 1.6398x over previous
//
#include <hip/hip_runtime.h>
#include <math.h>

#define N_NODES 8192
#define C_CLS   16
#define JC      256            // j-chunk staged in LDS per iteration
#define JSPLIT  4              // j-dimension split across blocks
#define JSLICE  (N_NODES / JSPLIT)   // 2048 columns per block
#define NCH     (JSLICE / JC)        // 8 chunks per block
#define RPB     16             // rows per block (4 waves x 4 rows)
#define MAXRG   (N_NODES / RPB)      // 512 row-groups max
#define ROWW    20             // floats per emitted row (16 dots + rowsum + pad)

// ---- workspace layout (bytes) ----
#define WS_INPUTS 0                  // 8192*16*4            = 524288
#define WS_HROW   524288             // 2048*16*20*4         = 2621440
#define WS_IDX    3145728            // 8192*4               = 32768
#define WS_CLS    3178496            // 8192*4               = 32768
#define WS_COUNTS 3211264            // 16*4 (padded)
#define WS_NM     3211392            // 4
#define WS_H16    3211456            // 256*4

// ---------------------------------------------------------------------------
// A: blocks 0..31: inputs = softmax(init_inputs) blended with one-hot(y).
//    block 32: ballot-based masked-row compaction + per-class counts + class
//    of each compacted row.
// ---------------------------------------------------------------------------
__global__ __launch_bounds__(256) void k_prep(const float* __restrict__ init_in,
                                              const int* __restrict__ y,
                                              const int* __restrict__ mask,
                                              float* __restrict__ inputs,
                                              int* __restrict__ idx,
                                              int* __restrict__ clsc,
                                              int* __restrict__ counts,
                                              int* __restrict__ nmp) {
  if (blockIdx.x < 32) {
    int i = blockIdx.x * 256 + threadIdx.x;
    const float4* p = (const float4*)(init_in + (size_t)i * C_CLS);
    float v[16];
    float4 a0 = p[0], a1 = p[1], a2 = p[2], a3 = p[3];
    v[0]=a0.x; v[1]=a0.y; v[2]=a0.z; v[3]=a0.w;
    v[4]=a1.x; v[5]=a1.y; v[6]=a1.z; v[7]=a1.w;
    v[8]=a2.x; v[9]=a2.y; v[10]=a2.z; v[11]=a2.w;
    v[12]=a3.x; v[13]=a3.y; v[14]=a3.z; v[15]=a3.w;
    float mx = v[0];
#pragma unroll
    for (int c = 1; c < 16; ++c) mx = fmaxf(mx, v[c]);
    float s = 0.f;
#pragma unroll
    for (int c = 0; c < 16; ++c) { v[c] = expf(v[c] - mx); s += v[c]; }
    float inv = 1.0f / s;
    if (mask[i] != 0) {
      int yc = y[i];
#pragma unroll
      for (int c = 0; c < 16; ++c) v[c] = (c == yc) ? 1.0f : 0.0f;
    } else {
#pragma unroll
      for (int c = 0; c < 16; ++c) v[c] *= inv;
    }
    float4* o = (float4*)(inputs + (size_t)i * C_CLS);
    o[0] = make_float4(v[0], v[1], v[2], v[3]);
    o[1] = make_float4(v[4], v[5], v[6], v[7]);
    o[2] = make_float4(v[8], v[9], v[10], v[11]);
    o[3] = make_float4(v[12], v[13], v[14], v[15]);
    return;
  }
  // ---- compaction block (4 waves, 2048 rows each) ----
  __shared__ unsigned long long bm_s[4][32];
  __shared__ int wtot[4];
  __shared__ int wcls[4][16];
  int lane = threadIdx.x & 63, w = threadIdx.x >> 6;
  int base = w * 2048;
  int cw = 0;
  int ccls[16];
#pragma unroll
  for (int c = 0; c < 16; ++c) ccls[c] = 0;
  for (int k = 0; k < 32; ++k) {
    int r = base + k * 64 + lane;
    int mv = mask[r];
    int yv = y[r];
    unsigned long long bm = __ballot(mv != 0);
    if (lane == 0) bm_s[w][k] = bm;
    cw += __popcll(bm);
#pragma unroll
    for (int c = 0; c < 16; ++c)
      ccls[c] += __popcll(__ballot((mv != 0) && (yv == c)));
  }
  if (lane == 0) {
    wtot[w] = cw;
#pragma unroll
    for (int c = 0; c < 16; ++c) wcls[w][c] = ccls[c];
  }
  __syncthreads();
  int run = 0;
  for (int u = 0; u < 4; ++u) run += (u < w) ? wtot[u] : 0;
  for (int k = 0; k < 32; ++k) {
    unsigned long long bm = bm_s[w][k];
    int r = base + k * 64 + lane;
    if ((bm >> lane) & 1ull) {
      int pos = run + __popcll(bm & ((1ull << lane) - 1ull));
      idx[pos] = r;
      clsc[pos] = y[r];
    }
    run += __popcll(bm);
  }
  if (threadIdx.x < 16)
    counts[threadIdx.x] = wcls[0][threadIdx.x] + wcls[1][threadIdx.x] +
                          wcls[2][threadIdx.x] + wcls[3][threadIdx.x];
  if (threadIdx.x == 0) nmp[0] = wtot[0] + wtot[1] + wtot[2] + wtot[3];
}

// ---------------------------------------------------------------------------
// B: per-row dot partials over a j-slice. Block (rg, js): 16 rows x 2048 cols.
// Register double-buffer of both A-loads and inputs staging loads (issue one
// chunk ahead, under the compute of the current chunk).
// ---------------------------------------------------------------------------
__global__ __launch_bounds__(256) void k_main(const float* __restrict__ A,
                                              const float* __restrict__ inputs,
                                              const int* __restrict__ idx,
                                              const int* __restrict__ nmp,
                                              float* __restrict__ Hrow) {
  __shared__ float lin[JC * 16];       // 16 KiB staged inputs chunk (swizzled)
  int tid = threadIdx.x, wid = tid >> 6, lane = tid & 63;
  int nm = *nmp;
  int bid = blockIdx.x;
  int rg = bid >> 2, js = bid & 3;
  if (rg * RPB >= nm) return;          // whole-block uniform

  int rbase = rg * RPB + wid * 4;
  bool valid[4];                       // wave-uniform
  const float* arow[4];
#pragma unroll
  for (int r = 0; r < 4; ++r) {
    int g = rbase + r;
    valid[r] = (g < nm);
    int row = valid[r] ? idx[g] : 0;
    arow[r] = A + (size_t)row * N_NODES;
  }

  float acc[4][16];
  float asum[4] = {0.f, 0.f, 0.f, 0.f};
#pragma unroll
  for (int r = 0; r < 4; ++r)
#pragma unroll
    for (int c = 0; c < 16; ++c) acc[r][c] = 0.f;

  int jbase = js * JSLICE;
  int jl = lane * 4;

  // prologue: chunk-0 loads
  float4 va[4], a4[4];
#pragma unroll
  for (int s = 0; s < 4; ++s)
    va[s] = *(const float4*)(inputs + (size_t)jbase * 16 + (size_t)(s * 256 + tid) * 4);
#pragma unroll
  for (int r = 0; r < 4; ++r)
    a4[r] = valid[r] ? *(const float4*)(arow[r] + jbase + jl)
                     : make_float4(0.f, 0.f, 0.f, 0.f);

  for (int ch = 0; ch < NCH; ++ch) {
    // stage current chunk into LDS (swizzled granules)
#pragma unroll
    for (int s = 0; s < 4; ++s) {
      int G = s * 256 + tid;
      int slot = G ^ ((G >> 4) & 7);
      *(float4*)(lin + slot * 4) = va[s];
    }
    __syncthreads();

    // issue next chunk's global loads under this chunk's compute
    float4 van[4], a4n[4];
    if (ch + 1 < NCH) {                // block-uniform branch
      int j0n = jbase + (ch + 1) * JC;
#pragma unroll
      for (int s = 0; s < 4; ++s)
        van[s] = *(const float4*)(inputs + (size_t)j0n * 16 + (size_t)(s * 256 + tid) * 4);
#pragma unroll
      for (int r = 0; r < 4; ++r)
        a4n[r] = valid[r] ? *(const float4*)(arow[r] + j0n + jl)
                          : make_float4(0.f, 0.f, 0.f, 0.f);
    } else {
#pragma unroll
      for (int s = 0; s < 4; ++s) van[s] = make_float4(0.f, 0.f, 0.f, 0.f);
#pragma unroll
      for (int r = 0; r < 4; ++r) a4n[r] = make_float4(0.f, 0.f, 0.f, 0.f);
    }

    // compute on current chunk
#pragma unroll
    for (int jj = 0; jj < 4; ++jj) {
      int g0 = (jl + jj) * 4;
      int sw = lane & 7;               // == ((jl+jj)>>2)&7
      float in[16];
#pragma unroll
      for (int c4 = 0; c4 < 4; ++c4) {
        float4 v = *(const float4*)(lin + ((g0 + c4) ^ sw) * 4);
        in[c4 * 4 + 0] = v.x; in[c4 * 4 + 1] = v.y;
        in[c4 * 4 + 2] = v.z; in[c4 * 4 + 3] = v.w;
      }
#pragma unroll
      for (int r = 0; r < 4; ++r) {
        float av = (jj == 0) ? a4[r].x : (jj == 1) ? a4[r].y
                 : (jj == 2) ? a4[r].z : a4[r].w;
        asum[r] += av;
#pragma unroll
        for (int c = 0; c < 16; ++c) acc[r][c] = fmaf(av, in[c], acc[r][c]);
      }
    }
    __syncthreads();
#pragma unroll
    for (int s = 0; s < 4; ++s) va[s] = van[s];
#pragma unroll
    for (int r = 0; r < 4; ++r) a4[r] = a4n[r];
  }

  // lane-reduce and emit per-row partials (no normalization here)
#pragma unroll
  for (int r = 0; r < 4; ++r) {
    float s = asum[r];
    float t16[16];
#pragma unroll
    for (int c = 0; c < 16; ++c) t16[c] = acc[r][c];
    for (int m = 1; m < 64; m <<= 1) {
      s += __shfl_xor(s, m, 64);
#pragma unroll
      for (int c = 0; c < 16; ++c) t16[c] += __shfl_xor(t16[c], m, 64);
    }
    float* dst = Hrow + ((size_t)bid * RPB + wid * 4 + r) * ROWW;
    if (lane < 16) dst[lane] = t16[lane];
    if (lane == 16) dst[16] = s;
  }
}

// ---------------------------------------------------------------------------
// C1: parallel deterministic combine. Block c accumulates class-c rows:
// 16 row-groups x 16 cols; fixed per-thread order; LDS tree reduce.
// ---------------------------------------------------------------------------
__global__ __launch_bounds__(256) void k_comb(const float* __restrict__ Hrow,
                                              const int* __restrict__ clsc,
                                              const int* __restrict__ nmp,
                                              float* __restrict__ H16) {
  int c = blockIdx.x, t = threadIdx.x, g = t >> 4, col = t & 15;
  int nm = *nmp;
  float acc = 0.f;
  for (int i = g; i < nm; i += 16) {
    if (clsc[i] != c) continue;
    const float* base = Hrow + (size_t)(i >> 4) * (JSPLIT * RPB * ROWW)
                             + (size_t)(i & 15) * ROWW;
    float dot = 0.f, rsum = 0.f;
#pragma unroll
    for (int js = 0; js < JSPLIT; ++js) {
      dot  += base[js * RPB * ROWW + col];
      rsum += base[js * RPB * ROWW + 16];
    }
    acc += dot / rsum;
  }
  __shared__ float red[16][17];
  red[g][col] = acc;
  __syncthreads();
  if (g == 0) {
    float s = 0.f;
    for (int k = 0; k < 16; ++k) s += red[k][col];
    H16[c * 16 + col] = s;
  }
}

// ---------------------------------------------------------------------------
// C2: counts divide, NaN repair, single-wave early-breaking Sinkhorn.
// ---------------------------------------------------------------------------
__global__ void k_sink(const float* __restrict__ H16,
                       const int* __restrict__ counts,
                       float* __restrict__ out) {
  __shared__ float S[256];
  __shared__ float S2[256];
  __shared__ float Sn[256];
  __shared__ float rs[16];
  __shared__ int nc[16];
  int t = threadIdx.x;
  int a = t >> 4, c = t & 15;
  float cnt = (float)counts[a];
  float H = H16[t] / cnt;               // 0/0 -> NaN, matches reference
  S[t] = H;
  __syncthreads();
  float HT = S[c * 16 + a];
  if (isnan(H)) H = HT;
  bool nan2 = isnan(H);
  float Hz = nan2 ? 0.f : H;
  S2[t] = Hz;
  Sn[t] = nan2 ? 1.f : 0.f;
  __syncthreads();
  if (t < 16) {
    float rsum = 0.f, ns = 0.f;
    for (int k = 0; k < 16; ++k) { rsum += S2[t * 16 + k]; ns += Sn[t * 16 + k]; }
    rs[t] = rsum; nc[t] = (int)ns;
  }
  __syncthreads();
  float miss = (1.0f - rs[a]) / (float)max(nc[a], 1);
  H = nan2 ? miss : Hz;
  __syncthreads();
  S[t] = H;
  __syncthreads();
  // single-wave Sinkhorn: lane holds col (t&15), rows rgq*4+k
  if (t < 64) {
    int lcol = t & 15, rgq = t >> 4;
    float h[4];
#pragma unroll
    for (int k = 0; k < 4; ++k) h[k] = S[(rgq * 4 + k) * 16 + lcol];
    for (int it = 0; it < 3000; ++it) {
      float p0 = h[0], p1 = h[1], p2 = h[2], p3 = h[3];
      float cs = (h[0] + h[1]) + (h[2] + h[3]);
      cs += __shfl_xor(cs, 16, 64);
      cs += __shfl_xor(cs, 32, 64);
      float rcs = __builtin_amdgcn_rcpf(cs);
#pragma unroll
      for (int k = 0; k < 4; ++k) h[k] *= rcs;
#pragma unroll
      for (int k = 0; k < 4; ++k) {
        float rv = h[k];
        rv += __shfl_xor(rv, 1, 64);
        rv += __shfl_xor(rv, 2, 64);
        rv += __shfl_xor(rv, 4, 64);
        rv += __shfl_xor(rv, 8, 64);
        h[k] *= __builtin_amdgcn_rcpf(rv);
      }
      float d = fabsf(h[0] - p0) + fabsf(h[1] - p1) +
                fabsf(h[2] - p2) + fabsf(h[3] - p3);
      d += __shfl_xor(d, 1, 64);  d += __shfl_xor(d, 2, 64);
      d += __shfl_xor(d, 4, 64);  d += __shfl_xor(d, 8, 64);
      d += __shfl_xor(d, 16, 64); d += __shfl_xor(d, 32, 64);
      if (d < 1e-5f) break;
    }
#pragma unroll
    for (int k = 0; k < 4; ++k) out[(rgq * 4 + k) * 16 + lcol] = h[k];
  }
}

// ---------------------------------------------------------------------------
extern "C" void kernel_launch(void* const* d_in, const int* in_sizes, int n_in,
                              void* d_out, int out_size, void* d_ws, size_t ws_size,
                              hipStream_t stream) {
  const float* A       = (const float*)d_in[0];  // raw_adj  (8192*8192)
  const float* init_in = (const float*)d_in[1];  // init_inputs (8192*16)
  const int*   y       = (const int*)d_in[2];    // (8192)
  const int*   mask    = (const int*)d_in[3];    // (8192)
  float* out = (float*)d_out;                    // (16*16)
  char*  ws  = (char*)d_ws;
  float* inputs = (float*)(ws + WS_INPUTS);
  float* Hrow   = (float*)(ws + WS_HROW);
  int*   idx    = (int*)(ws + WS_IDX);
  int*   clsc   = (int*)(ws + WS_CLS);
  int*   counts = (int*)(ws + WS_COUNTS);
  int*   nmp    = (int*)(ws + WS_NM);
  float* H16    = (float*)(ws + WS_H16);

  k_prep<<<33, 256, 0, stream>>>(init_in, y, mask, inputs, idx, clsc, counts, nmp);
  k_main<<<MAXRG * JSPLIT, 256, 0, stream>>>(A, inputs, idx, nmp, Hrow);
  k_comb<<<16, 256, 0, stream>>>(Hrow, clsc, nmp, H16);
  k_sink<<<1, 256, 0, stream>>>(H16, counts, out);
}

// Round 5
// 88.231 us; speedup vs baseline: 2.8008x; 1.7080x over previous
//
#include <hip/hip_runtime.h>
#include <math.h>

#define N_NODES 8192
#define C_CLS   16
#define JC      256            // j-chunk staged in LDS per iteration
#define JSPLIT  4              // j-dimension split across blocks
#define JSLICE  (N_NODES / JSPLIT)   // 2048 columns per block
#define NCH     (JSLICE / JC)        // 8 chunks per block
#define RPB     16             // rows per block (4 waves x 4 rows)
#define MAXRG   (N_NODES / RPB)      // 512 row-groups max
#define ROWW    20             // floats per emitted row (16 dots + rowsum + pad)
#define CB_ROWS 64             // compacted rows per k_comb block
#define NB_COMB (N_NODES / CB_ROWS)  // 128

// ---- workspace layout (bytes) ----
#define WS_INPUTS 0                  // 8192*16*4            = 524288
#define WS_HROW   524288             // 2048*16*20*4         = 2621440
#define WS_IDX    3145728            // 8192*4               = 32768
#define WS_CLS    3178496            // 8192*4               = 32768
#define WS_COUNTS 3211264            // 16*4 (padded)
#define WS_NM     3211392            // 4 (padded)
#define WS_HPART  3211520            // 128*256*4            = 131072

// ---------------------------------------------------------------------------
// A: blocks 0..31: inputs = softmax(init_inputs) blended with one-hot(y).
//    block 32: ballot-based masked-row compaction + per-class counts + class
//    of each compacted row.  (unchanged from R4)
// ---------------------------------------------------------------------------
__global__ __launch_bounds__(256) void k_prep(const float* __restrict__ init_in,
                                              const int* __restrict__ y,
                                              const int* __restrict__ mask,
                                              float* __restrict__ inputs,
                                              int* __restrict__ idx,
                                              int* __restrict__ clsc,
                                              int* __restrict__ counts,
                                              int* __restrict__ nmp) {
  if (blockIdx.x < 32) {
    int i = blockIdx.x * 256 + threadIdx.x;
    const float4* p = (const float4*)(init_in + (size_t)i * C_CLS);
    float v[16];
    float4 a0 = p[0], a1 = p[1], a2 = p[2], a3 = p[3];
    v[0]=a0.x; v[1]=a0.y; v[2]=a0.z; v[3]=a0.w;
    v[4]=a1.x; v[5]=a1.y; v[6]=a1.z; v[7]=a1.w;
    v[8]=a2.x; v[9]=a2.y; v[10]=a2.z; v[11]=a2.w;
    v[12]=a3.x; v[13]=a3.y; v[14]=a3.z; v[15]=a3.w;
    float mx = v[0];
#pragma unroll
    for (int c = 1; c < 16; ++c) mx = fmaxf(mx, v[c]);
    float s = 0.f;
#pragma unroll
    for (int c = 0; c < 16; ++c) { v[c] = expf(v[c] - mx); s += v[c]; }
    float inv = 1.0f / s;
    if (mask[i] != 0) {
      int yc = y[i];
#pragma unroll
      for (int c = 0; c < 16; ++c) v[c] = (c == yc) ? 1.0f : 0.0f;
    } else {
#pragma unroll
      for (int c = 0; c < 16; ++c) v[c] *= inv;
    }
    float4* o = (float4*)(inputs + (size_t)i * C_CLS);
    o[0] = make_float4(v[0], v[1], v[2], v[3]);
    o[1] = make_float4(v[4], v[5], v[6], v[7]);
    o[2] = make_float4(v[8], v[9], v[10], v[11]);
    o[3] = make_float4(v[12], v[13], v[14], v[15]);
    return;
  }
  // ---- compaction block (4 waves, 2048 rows each) ----
  __shared__ unsigned long long bm_s[4][32];
  __shared__ int wtot[4];
  __shared__ int wcls[4][16];
  int lane = threadIdx.x & 63, w = threadIdx.x >> 6;
  int base = w * 2048;
  int cw = 0;
  int ccls[16];
#pragma unroll
  for (int c = 0; c < 16; ++c) ccls[c] = 0;
  for (int k = 0; k < 32; ++k) {
    int r = base + k * 64 + lane;
    int mv = mask[r];
    int yv = y[r];
    unsigned long long bm = __ballot(mv != 0);
    if (lane == 0) bm_s[w][k] = bm;
    cw += __popcll(bm);
#pragma unroll
    for (int c = 0; c < 16; ++c)
      ccls[c] += __popcll(__ballot((mv != 0) && (yv == c)));
  }
  if (lane == 0) {
    wtot[w] = cw;
#pragma unroll
    for (int c = 0; c < 16; ++c) wcls[w][c] = ccls[c];
  }
  __syncthreads();
  int run = 0;
  for (int u = 0; u < 4; ++u) run += (u < w) ? wtot[u] : 0;
  for (int k = 0; k < 32; ++k) {
    unsigned long long bm = bm_s[w][k];
    int r = base + k * 64 + lane;
    if ((bm >> lane) & 1ull) {
      int pos = run + __popcll(bm & ((1ull << lane) - 1ull));
      idx[pos] = r;
      clsc[pos] = y[r];
    }
    run += __popcll(bm);
  }
  if (threadIdx.x < 16)
    counts[threadIdx.x] = wcls[0][threadIdx.x] + wcls[1][threadIdx.x] +
                          wcls[2][threadIdx.x] + wcls[3][threadIdx.x];
  if (threadIdx.x == 0) nmp[0] = wtot[0] + wtot[1] + wtot[2] + wtot[3];
}

// ---------------------------------------------------------------------------
// B: per-row dot partials over a j-slice. Block (rg, js): 16 rows x 2048 cols.
// Register double-buffer of A-loads and inputs staging loads. (unchanged)
// ---------------------------------------------------------------------------
__global__ __launch_bounds__(256) void k_main(const float* __restrict__ A,
                                              const float* __restrict__ inputs,
                                              const int* __restrict__ idx,
                                              const int* __restrict__ nmp,
                                              float* __restrict__ Hrow) {
  __shared__ float lin[JC * 16];       // 16 KiB staged inputs chunk (swizzled)
  int tid = threadIdx.x, wid = tid >> 6, lane = tid & 63;
  int nm = *nmp;
  int bid = blockIdx.x;
  int rg = bid >> 2, js = bid & 3;
  if (rg * RPB >= nm) return;          // whole-block uniform

  int rbase = rg * RPB + wid * 4;
  bool valid[4];                       // wave-uniform
  const float* arow[4];
#pragma unroll
  for (int r = 0; r < 4; ++r) {
    int g = rbase + r;
    valid[r] = (g < nm);
    int row = valid[r] ? idx[g] : 0;
    arow[r] = A + (size_t)row * N_NODES;
  }

  float acc[4][16];
  float asum[4] = {0.f, 0.f, 0.f, 0.f};
#pragma unroll
  for (int r = 0; r < 4; ++r)
#pragma unroll
    for (int c = 0; c < 16; ++c) acc[r][c] = 0.f;

  int jbase = js * JSLICE;
  int jl = lane * 4;

  // prologue: chunk-0 loads
  float4 va[4], a4[4];
#pragma unroll
  for (int s = 0; s < 4; ++s)
    va[s] = *(const float4*)(inputs + (size_t)jbase * 16 + (size_t)(s * 256 + tid) * 4);
#pragma unroll
  for (int r = 0; r < 4; ++r)
    a4[r] = valid[r] ? *(const float4*)(arow[r] + jbase + jl)
                     : make_float4(0.f, 0.f, 0.f, 0.f);

  for (int ch = 0; ch < NCH; ++ch) {
#pragma unroll
    for (int s = 0; s < 4; ++s) {
      int G = s * 256 + tid;
      int slot = G ^ ((G >> 4) & 7);
      *(float4*)(lin + slot * 4) = va[s];
    }
    __syncthreads();

    float4 van[4], a4n[4];
    if (ch + 1 < NCH) {                // block-uniform branch
      int j0n = jbase + (ch + 1) * JC;
#pragma unroll
      for (int s = 0; s < 4; ++s)
        van[s] = *(const float4*)(inputs + (size_t)j0n * 16 + (size_t)(s * 256 + tid) * 4);
#pragma unroll
      for (int r = 0; r < 4; ++r)
        a4n[r] = valid[r] ? *(const float4*)(arow[r] + j0n + jl)
                          : make_float4(0.f, 0.f, 0.f, 0.f);
    } else {
#pragma unroll
      for (int s = 0; s < 4; ++s) van[s] = make_float4(0.f, 0.f, 0.f, 0.f);
#pragma unroll
      for (int r = 0; r < 4; ++r) a4n[r] = make_float4(0.f, 0.f, 0.f, 0.f);
    }

#pragma unroll
    for (int jj = 0; jj < 4; ++jj) {
      int g0 = (jl + jj) * 4;
      int sw = lane & 7;               // == ((jl+jj)>>2)&7
      float in[16];
#pragma unroll
      for (int c4 = 0; c4 < 4; ++c4) {
        float4 v = *(const float4*)(lin + ((g0 + c4) ^ sw) * 4);
        in[c4 * 4 + 0] = v.x; in[c4 * 4 + 1] = v.y;
        in[c4 * 4 + 2] = v.z; in[c4 * 4 + 3] = v.w;
      }
#pragma unroll
      for (int r = 0; r < 4; ++r) {
        float av = (jj == 0) ? a4[r].x : (jj == 1) ? a4[r].y
                 : (jj == 2) ? a4[r].z : a4[r].w;
        asum[r] += av;
#pragma unroll
        for (int c = 0; c < 16; ++c) acc[r][c] = fmaf(av, in[c], acc[r][c]);
      }
    }
    __syncthreads();
#pragma unroll
    for (int s = 0; s < 4; ++s) va[s] = van[s];
#pragma unroll
    for (int r = 0; r < 4; ++r) a4[r] = a4n[r];
  }

#pragma unroll
  for (int r = 0; r < 4; ++r) {
    float s = asum[r];
    float t16[16];
#pragma unroll
    for (int c = 0; c < 16; ++c) t16[c] = acc[r][c];
    for (int m = 1; m < 64; m <<= 1) {
      s += __shfl_xor(s, m, 64);
#pragma unroll
      for (int c = 0; c < 16; ++c) t16[c] += __shfl_xor(t16[c], m, 64);
    }
    float* dst = Hrow + ((size_t)bid * RPB + wid * 4 + r) * ROWW;
    if (lane < 16) dst[lane] = t16[lane];
    if (lane == 16) dst[16] = s;
  }
}

// ---------------------------------------------------------------------------
// C1: parallel deterministic combine v2. Block b owns compacted rows
// [b*64, b*64+64); wave w handles 16 of them sequentially. All 64 lanes
// cooperate per row: lane = jsg*16+col loads the 4 j-slice partials,
// shfl_xor(16,32) folds -> dot[col] + full rowsum; one ordered LDS add
// per row into per-wave class matrix. Deterministic: sequential within
// wave, disjoint hp[wid], fixed block order in k_sink's sum.
// ---------------------------------------------------------------------------
__global__ __launch_bounds__(256) void k_comb(const float* __restrict__ Hrow,
                                              const int* __restrict__ clsc,
                                              const int* __restrict__ nmp,
                                              float* __restrict__ Hpart) {
  __shared__ float hp[4][16][16];
  int t = threadIdx.x, wid = t >> 6, lane = t & 63;
  int b = blockIdx.x;
  int nm = *nmp;
  ((float*)hp)[t] = 0.f; ((float*)hp)[t + 256] = 0.f;
  ((float*)hp)[t + 512] = 0.f; ((float*)hp)[t + 768] = 0.f;
  __syncthreads();
  int jsg = lane >> 4;                 // which j-slice partial this lane reads
  int base_i = b * CB_ROWS + wid * 16;
#pragma unroll 4
  for (int k = 0; k < 16; ++k) {
    int i = base_i + k;
    if (i >= nm) break;                // wave-uniform
    const float* bp = Hrow + (size_t)(i >> 4) * (JSPLIT * RPB * ROWW)
                           + (size_t)(i & 15) * ROWW
                           + (size_t)jsg * (RPB * ROWW);
    float dv = bp[lane & 15];
    float rv = bp[16];
    dv += __shfl_xor(dv, 16, 64);
    dv += __shfl_xor(dv, 32, 64);
    rv += __shfl_xor(rv, 16, 64);
    rv += __shfl_xor(rv, 32, 64);
    float d = dv / rv;                 // normalized dot for col = lane&15
    int cls = clsc[i];                 // wave-uniform broadcast
    if (lane < 16) hp[wid][cls][lane] += d;
  }
  __syncthreads();
  int a = t >> 4, c = t & 15;
  Hpart[(size_t)b * 256 + t] =
      hp[0][a][c] + hp[1][a][c] + hp[2][a][c] + hp[3][a][c];
}

// ---------------------------------------------------------------------------
// C2: sum 128 block partials (fixed order), counts divide, NaN repair,
// single-wave early-breaking Sinkhorn.
// ---------------------------------------------------------------------------
__global__ void k_sink(const float* __restrict__ Hpart,
                       const int* __restrict__ counts,
                       float* __restrict__ out) {
  __shared__ float S[256];
  __shared__ float S2[256];
  __shared__ float Sn[256];
  __shared__ float rs[16];
  __shared__ int nc[16];
  int t = threadIdx.x;
  int a = t >> 4, c = t & 15;
  float s = 0.f;
#pragma unroll 16
  for (int b = 0; b < NB_COMB; ++b) s += Hpart[(size_t)b * 256 + t];
  float cnt = (float)counts[a];
  float H = s / cnt;                    // 0/0 -> NaN, matches reference
  S[t] = H;
  __syncthreads();
  float HT = S[c * 16 + a];
  if (isnan(H)) H = HT;
  bool nan2 = isnan(H);
  float Hz = nan2 ? 0.f : H;
  S2[t] = Hz;
  Sn[t] = nan2 ? 1.f : 0.f;
  __syncthreads();
  if (t < 16) {
    float rsum = 0.f, ns = 0.f;
    for (int k = 0; k < 16; ++k) { rsum += S2[t * 16 + k]; ns += Sn[t * 16 + k]; }
    rs[t] = rsum; nc[t] = (int)ns;
  }
  __syncthreads();
  float miss = (1.0f - rs[a]) / (float)max(nc[a], 1);
  H = nan2 ? miss : Hz;
  __syncthreads();
  S[t] = H;
  __syncthreads();
  if (t < 64) {
    int lcol = t & 15, rgq = t >> 4;
    float h[4];
#pragma unroll
    for (int k = 0; k < 4; ++k) h[k] = S[(rgq * 4 + k) * 16 + lcol];
    for (int it = 0; it < 3000; ++it) {
      float p0 = h[0], p1 = h[1], p2 = h[2], p3 = h[3];
      float cs = (h[0] + h[1]) + (h[2] + h[3]);
      cs += __shfl_xor(cs, 16, 64);
      cs += __shfl_xor(cs, 32, 64);
      float rcs = __builtin_amdgcn_rcpf(cs);
#pragma unroll
      for (int k = 0; k < 4; ++k) h[k] *= rcs;
#pragma unroll
      for (int k = 0; k < 4; ++k) {
        float rv = h[k];
        rv += __shfl_xor(rv, 1, 64);
        rv += __shfl_xor(rv, 2, 64);
        rv += __shfl_xor(rv, 4, 64);
        rv += __shfl_xor(rv, 8, 64);
        h[k] *= __builtin_amdgcn_rcpf(rv);
      }
      float d = fabsf(h[0] - p0) + fabsf(h[1] - p1) +
                fabsf(h[2] - p2) + fabsf(h[3] - p3);
      d += __shfl_xor(d, 1, 64);  d += __shfl_xor(d, 2, 64);
      d += __shfl_xor(d, 4, 64);  d += __shfl_xor(d, 8, 64);
      d += __shfl_xor(d, 16, 64); d += __shfl_xor(d, 32, 64);
      if (d < 1e-5f) break;
    }
#pragma unroll
    for (int k = 0; k < 4; ++k) out[(rgq * 4 + k) * 16 + lcol] = h[k];
  }
}

// ---------------------------------------------------------------------------
extern "C" void kernel_launch(void* const* d_in, const int* in_sizes, int n_in,
                              void* d_out, int out_size, void* d_ws, size_t ws_size,
                              hipStream_t stream) {
  const float* A       = (const float*)d_in[0];  // raw_adj  (8192*8192)
  const float* init_in = (const float*)d_in[1];  // init_inputs (8192*16)
  const int*   y       = (const int*)d_in[2];    // (8192)
  const int*   mask    = (const int*)d_in[3];    // (8192)
  float* out = (float*)d_out;                    // (16*16)
  char*  ws  = (char*)d_ws;
  float* inputs = (float*)(ws + WS_INPUTS);
  float* Hrow   = (float*)(ws + WS_HROW);
  int*   idx    = (int*)(ws + WS_IDX);
  int*   clsc   = (int*)(ws + WS_CLS);
  int*   counts = (int*)(ws + WS_COUNTS);
  int*   nmp    = (int*)(ws + WS_NM);
  float* Hpart  = (float*)(ws + WS_HPART);

  k_prep<<<33, 256, 0, stream>>>(init_in, y, mask, inputs, idx, clsc, counts, nmp);
  k_main<<<MAXRG * JSPLIT, 256, 0, stream>>>(A, inputs, idx, nmp, Hrow);
  k_comb<<<NB_COMB, 256, 0, stream>>>(Hrow, clsc, nmp, Hpart);
  k_sink<<<1, 256, 0, stream>>>(Hpart, counts, out);
}